// Round 4
// baseline (154.501 us; speedup 1.0000x reference)
//
#include <hip/hip_runtime.h>
#include <hip/hip_bf16.h>

// Problem constants (from reference)
constexpr int B = 8;
constexpr int L = 2048;
constexpr int ANG = 16;
constexpr int AMP = 48;
constexpr int H = 4;
constexpr int AQK = 12, GQK = 6;
constexpr int AV = 12, GV = 6;
constexpr int HD = 2 * GQK + AQK;      // 24 = per-head q/k/v dim
constexpr int LOOKBACK = 100;

constexpr int NTOK = B * L;            // 16384 tokens

// -------------------- Kernel 1: fused QKV projections --------------------
// (unchanged from round 3 — role chosen per block, no intra-wave divergence)
constexpr int QKV_AMP_JOBS = NTOK * 48;              // 786432
constexpr int QKV_ANG_JOBS = NTOK * 72;              // 1179648
constexpr int QKV_AMP_BLOCKS = QKV_AMP_JOBS / 256;   // 3072
constexpr int QKV_ANG_BLOCKS = QKV_ANG_JOBS / 256;   // 4608

__global__ __launch_bounds__(256) void qkv2_kernel(
    const float* __restrict__ x_ang, const float* __restrict__ x_amp,
    const float* __restrict__ Wq_amp, const float* __restrict__ Wk_amp,
    const float* __restrict__ Wv_amp,
    const float* __restrict__ Wq_ang_r, const float* __restrict__ Wq_ang_i,
    const float* __restrict__ Wk_ang_r, const float* __restrict__ Wk_ang_i,
    const float* __restrict__ Wv_ang_r, const float* __restrict__ Wv_ang_i,
    float* __restrict__ q, float* __restrict__ k, float* __restrict__ v)
{
    int bid = blockIdx.x;
    if (bid < QKV_AMP_BLOCKS) {
        int g   = bid * 256 + threadIdx.x;
        int col = g % 48;               // h*12 + ca
        int tok = g / 48;

        const float4* xm4 = (const float4*)(x_amp + (size_t)tok * AMP);
        float x[48];
        #pragma unroll
        for (int i = 0; i < 12; i++) {
            float4 t = xm4[i];
            x[4*i+0] = t.x; x[4*i+1] = t.y; x[4*i+2] = t.z; x[4*i+3] = t.w;
        }

        float aq = 0.f, ak = 0.f, av = 0.f;
        #pragma unroll
        for (int i = 0; i < 48; i++) {
            aq += x[i] * Wq_amp[i * 48 + col];
            ak += x[i] * Wk_amp[i * 48 + col];
            av += x[i] * Wv_amp[i * 48 + col];
        }

        int b = tok / L, l = tok % L;
        int h = col / 12, ca = col % 12;
        size_t o = (((size_t)b * H + h) * L + l) * HD + (2 * GQK) + ca;
        q[o] = aq; k[o] = ak; v[o] = av;
    } else {
        int g     = (bid - QKV_AMP_BLOCKS) * 256 + threadIdx.x;
        int j     = g % 72;
        int tok   = g / 72;
        int mat   = j / 24;             // 0=q 1=k 2=v
        int combo = j % 24;             // = weight col = h*6+dd
        int h     = combo / 6, dd = combo % 6;

        const float4* xa4 = (const float4*)(x_ang + (size_t)tok * (2 * ANG));
        float xr[16], xi[16];
        #pragma unroll
        for (int i = 0; i < 4; i++) {
            float4 t = xa4[i];
            xr[4*i+0] = t.x; xr[4*i+1] = t.y; xr[4*i+2] = t.z; xr[4*i+3] = t.w;
            float4 u = xa4[4 + i];
            xi[4*i+0] = u.x; xi[4*i+1] = u.y; xi[4*i+2] = u.z; xi[4*i+3] = u.w;
        }

        const float* Wr = (mat == 0) ? Wq_ang_r : (mat == 1) ? Wk_ang_r : Wv_ang_r;
        const float* Wi = (mat == 0) ? Wq_ang_i : (mat == 1) ? Wk_ang_i : Wv_ang_i;

        float orr = 0.f, oii = 0.f;
        #pragma unroll
        for (int i = 0; i < 16; i++) {
            float wr = Wr[i * 24 + combo], wi = Wi[i * 24 + combo];
            orr += xr[i] * wr - xi[i] * wi;
            oii += xr[i] * wi + xi[i] * wr;
        }

        float* dst = (mat == 0) ? q : (mat == 1) ? k : v;
        int b = tok / L, l = tok % L;
        size_t base = (((size_t)b * H + h) * L + l) * HD;
        dst[base + dd]       = orr;
        dst[base + GQK + dd] = oii;
    }
}

// -------------------- Kernel 2: banded causal attention (v3) --------------------
// Block = (b,h, 64-query tile), 256 threads = 4 parity split-K groups.
// K/V in LDS as float4 rows of 8 slots (128B stride) with XOR swizzle
// slot = q4 ^ (r&7): 8 consecutive lanes (consecutive rows) hit all 8
// quad-banks -> conflict-free ds_read_b128 (m214 recipe).
constexpr int TQA    = 64;
constexpr int GROUPS = 4;
constexpr int MAXKA  = TQA + LOOKBACK - 1; // 163

__global__ __launch_bounds__(256) void attn3_kernel(
    const float* __restrict__ q, const float* __restrict__ k,
    const float* __restrict__ v, float* __restrict__ att)
{
    constexpr int NT = L / TQA; // 32
    int bh = blockIdx.x / NT;
    int qt = blockIdx.x % NT;
    int q0 = qt * TQA;
    int kmin = q0 - (LOOKBACK - 1); if (kmin < 0) kmin = 0;
    int nrows = (q0 + TQA - 1) - kmin + 1; // <= 163

    __shared__ float4 Ks4[MAXKA][8];
    __shared__ float4 Vs4[MAXKA][8];
    __shared__ float  Pm[GROUPS][TQA];
    __shared__ float  Ps[GROUPS][TQA];
    __shared__ float4 Po4[GROUPS][TQA][6];

    // stage K/V rows [kmin, kmin+nrows): global float4 coalesced, swizzled LDS
    {
        const float4* kb4 = (const float4*)(k + ((size_t)bh * L + kmin) * HD);
        const float4* vb4 = (const float4*)(v + ((size_t)bh * L + kmin) * HD);
        int nch = nrows * 6;
        for (int c = threadIdx.x; c < nch; c += 256) {
            int r = c / 6, s = c % 6;
            int slot = s ^ (r & 7);
            Ks4[r][slot] = kb4[c];
            Vs4[r][slot] = vb4[c];
        }
    }
    __syncthreads();

    int qlocal = threadIdx.x & (TQA - 1);
    int group  = threadIdx.x >> 6;      // 0..3
    int qi = q0 + qlocal;

    float4 qr4[6];
    {
        const float4* qp4 = (const float4*)(q + ((size_t)bh * L + qi) * HD);
        #pragma unroll
        for (int s = 0; s < 6; s++) qr4[s] = qp4[s];
    }

    const float scale = 0.2041241452319315f; // 1/sqrt(24)
    float m = -3.0e38f, ss = 0.f;
    float4 o4[6];
    #pragma unroll
    for (int s = 0; s < 6; s++) { o4[s].x = 0.f; o4[s].y = 0.f; o4[s].z = 0.f; o4[s].w = 0.f; }

    int j0 = qi - (LOOKBACK - 1); if (j0 < 0) j0 = 0;
    for (int j = j0 + group; j <= qi; j += GROUPS) {
        int r  = j - kmin;
        int rx = r & 7;
        float sc = 0.f;
        #pragma unroll
        for (int s = 0; s < 6; s++) {
            float4 kk = Ks4[r][s ^ rx];
            sc += qr4[s].x * kk.x + qr4[s].y * kk.y + qr4[s].z * kk.z + qr4[s].w * kk.w;
        }
        sc *= scale;
        float mn   = fmaxf(m, sc);
        float corr = __expf(m - mn);
        float p    = __expf(sc - mn);
        ss = ss * corr + p;
        #pragma unroll
        for (int s = 0; s < 6; s++) {
            float4 vv = Vs4[r][s ^ rx];
            o4[s].x = o4[s].x * corr + p * vv.x;
            o4[s].y = o4[s].y * corr + p * vv.y;
            o4[s].z = o4[s].z * corr + p * vv.z;
            o4[s].w = o4[s].w * corr + p * vv.w;
        }
        m = mn;
    }

    Pm[group][qlocal] = m;
    Ps[group][qlocal] = ss;
    #pragma unroll
    for (int s = 0; s < 6; s++) Po4[group][qlocal][s] = o4[s];
    __syncthreads();

    // parallel merge: 256 threads = 64 queries x 4 chunks of float4-slots
    {
        int qq    = threadIdx.x & 63;
        int chunk = threadIdx.x >> 6;   // 0..3 -> slots {0,4},{1,5},{2},{3}
        float m0 = Pm[0][qq], m1 = Pm[1][qq], m2 = Pm[2][qq], m3 = Pm[3][qq];
        float mm = fmaxf(fmaxf(m0, m1), fmaxf(m2, m3));
        float c0 = __expf(m0 - mm), c1 = __expf(m1 - mm);
        float c2 = __expf(m2 - mm), c3 = __expf(m3 - mm);
        float denom = Ps[0][qq] * c0 + Ps[1][qq] * c1 + Ps[2][qq] * c2 + Ps[3][qq] * c3;
        float inv = 1.f / denom;

        float4* op4 = (float4*)(att + ((size_t)bh * L + q0 + qq) * HD);

        int s = chunk;
        {
            float4 a0 = Po4[0][qq][s], a1 = Po4[1][qq][s], a2 = Po4[2][qq][s], a3 = Po4[3][qq][s];
            float4 acc;
            acc.x = (a0.x * c0 + a1.x * c1 + a2.x * c2 + a3.x * c3) * inv;
            acc.y = (a0.y * c0 + a1.y * c1 + a2.y * c2 + a3.y * c3) * inv;
            acc.z = (a0.z * c0 + a1.z * c1 + a2.z * c2 + a3.z * c3) * inv;
            acc.w = (a0.w * c0 + a1.w * c1 + a2.w * c2 + a3.w * c3) * inv;
            op4[s] = acc;
        }
        if (chunk < 2) {
            s = chunk + 4;
            float4 a0 = Po4[0][qq][s], a1 = Po4[1][qq][s], a2 = Po4[2][qq][s], a3 = Po4[3][qq][s];
            float4 acc;
            acc.x = (a0.x * c0 + a1.x * c1 + a2.x * c2 + a3.x * c3) * inv;
            acc.y = (a0.y * c0 + a1.y * c1 + a2.y * c2 + a3.y * c3) * inv;
            acc.z = (a0.z * c0 + a1.z * c1 + a2.z * c2 + a3.z * c3) * inv;
            acc.w = (a0.w * c0 + a1.w * c1 + a2.w * c2 + a3.w * c3) * inv;
            op4[s] = acc;
        }
    }
}

// -------------------- Kernel 3: output projections --------------------
// (unchanged from round 3)
constexpr int PAMP_JOBS   = NTOK * 48;             // 786432
constexpr int PANG_JOBS   = NTOK * 16;             // 262144
constexpr int PAMP_BLOCKS = PAMP_JOBS / 256;       // 3072
constexpr int PANG_BLOCKS = PANG_JOBS / 256;       // 1024

__global__ __launch_bounds__(256) void proj2_kernel(
    const float* __restrict__ att,
    const float* __restrict__ Wout_amp, const float* __restrict__ bout_amp,
    const float* __restrict__ Wout_ang_r, const float* __restrict__ Wout_ang_i,
    float* __restrict__ out)
{
    constexpr size_t ANG_OUT = (size_t)NTOK * ANG; // 262144
    int bid = blockIdx.x;

    if (bid < PAMP_BLOCKS) {
        int g   = bid * 256 + threadIdx.x;
        int col = g % 48;
        int tok = g / 48;
        int b = tok / L, l = tok % L;

        float a[48];
        #pragma unroll
        for (int h = 0; h < H; h++) {
            const float4* ap4 = (const float4*)(att + (((size_t)b * H + h) * L + l) * HD + 2 * GV);
            #pragma unroll
            for (int i = 0; i < 3; i++) {
                float4 t = ap4[i];
                a[h*12 + 4*i+0] = t.x; a[h*12 + 4*i+1] = t.y;
                a[h*12 + 4*i+2] = t.z; a[h*12 + 4*i+3] = t.w;
            }
        }
        float acc = bout_amp[col];
        #pragma unroll
        for (int i = 0; i < 48; i++)
            acc += a[i] * Wout_amp[i * AMP + col];
        out[2 * ANG_OUT + (size_t)tok * AMP + col] = acc;
    } else {
        int g   = (bid - PAMP_BLOCKS) * 256 + threadIdx.x;
        int col = g % 16;
        int tok = g / 16;
        int b = tok / L, l = tok % L;

        float ar[24], ai[24];
        #pragma unroll
        for (int h = 0; h < H; h++) {
            const float4* ap4 = (const float4*)(att + (((size_t)b * H + h) * L + l) * HD);
            float4 t0 = ap4[0], t1 = ap4[1], t2 = ap4[2];
            ar[h*6+0] = t0.x; ar[h*6+1] = t0.y; ar[h*6+2] = t0.z; ar[h*6+3] = t0.w;
            ar[h*6+4] = t1.x; ar[h*6+5] = t1.y;
            ai[h*6+0] = t1.z; ai[h*6+1] = t1.w;
            ai[h*6+2] = t2.x; ai[h*6+3] = t2.y; ai[h*6+4] = t2.z; ai[h*6+5] = t2.w;
        }
        float accr = 0.f, acci = 0.f;
        #pragma unroll
        for (int i = 0; i < 24; i++) {
            float wr = Wout_ang_r[i * ANG + col], wi = Wout_ang_i[i * ANG + col];
            accr += ar[i] * wr - ai[i] * wi;
            acci += ar[i] * wi + ai[i] * wr;
        }
        out[(size_t)tok * ANG + col]           = accr;
        out[ANG_OUT + (size_t)tok * ANG + col] = acci;
    }
}

// -------------------- Launch --------------------
extern "C" void kernel_launch(void* const* d_in, const int* in_sizes, int n_in,
                              void* d_out, int out_size, void* d_ws, size_t ws_size,
                              hipStream_t stream)
{
    const float* x_ang      = (const float*)d_in[0];
    const float* x_amp      = (const float*)d_in[1];
    const float* Wq_amp     = (const float*)d_in[2];
    const float* Wk_amp     = (const float*)d_in[3];
    const float* Wv_amp     = (const float*)d_in[4];
    const float* Wq_ang_r   = (const float*)d_in[5];
    const float* Wq_ang_i   = (const float*)d_in[6];
    const float* Wk_ang_r   = (const float*)d_in[7];
    const float* Wk_ang_i   = (const float*)d_in[8];
    const float* Wv_ang_r   = (const float*)d_in[9];
    const float* Wv_ang_i   = (const float*)d_in[10];
    const float* Wout_amp   = (const float*)d_in[11];
    const float* bout_amp   = (const float*)d_in[12];
    const float* Wout_ang_r = (const float*)d_in[13];
    const float* Wout_ang_i = (const float*)d_in[14];

    float* out = (float*)d_out;
    float* ws  = (float*)d_ws;

    const size_t N = (size_t)B * H * L * HD; // 1,572,864 floats per buffer
    float* q   = ws;
    float* k   = ws + N;
    float* v   = ws + 2 * N;
    float* att = ws + 3 * N;

    qkv2_kernel<<<QKV_AMP_BLOCKS + QKV_ANG_BLOCKS, 256, 0, stream>>>(
        x_ang, x_amp, Wq_amp, Wk_amp, Wv_amp,
        Wq_ang_r, Wq_ang_i, Wk_ang_r, Wk_ang_i, Wv_ang_r, Wv_ang_i,
        q, k, v);

    attn3_kernel<<<B * H * (L / TQA), 256, 0, stream>>>(q, k, v, att);

    proj2_kernel<<<PAMP_BLOCKS + PANG_BLOCKS, 256, 0, stream>>>(
        att, Wout_amp, bout_amp, Wout_ang_r, Wout_ang_i, out);
}

// Round 5
// 153.206 us; speedup vs baseline: 1.0085x; 1.0085x over previous
//
#include <hip/hip_runtime.h>
#include <hip/hip_bf16.h>

// Problem constants (from reference)
constexpr int B = 8;
constexpr int L = 2048;
constexpr int ANG = 16;
constexpr int AMP = 48;
constexpr int H = 4;
constexpr int AQK = 12, GQK = 6;
constexpr int AV = 12, GV = 6;
constexpr int HD = 2 * GQK + AQK;      // 24
constexpr int LOOKBACK = 100;
constexpr int NTOK = B * L;            // 16384

// ---------------- Fused kernel: QKV projection + banded attention ----------------
// Block = (b, h, 64-query tile). 256 threads.
// Phase A: stage x rows [kmin, q0+63] into LDS (padded: 49/33 floats per row).
// Phase B: compute k,v for all staged rows (threads 0..nrows-1) and q for the
//          64 query rows (threads 192..255) into registers; s-outer loop makes
//          every pass wave-uniform and weight loads wave-broadcast (L1-hot).
// Phase B2: write K/V into XOR-swizzled float4 tile (slot = s ^ (r&7)) that
//          REUSES the x-staging LDS via a union; Q into [64][6] tile.
// Phase C: 4-group parity split-K online softmax + exact LDS merge (attn3 core,
//          verified R3/R4). att written token-major: att[tok][h][24].
constexpr int TQ     = 64;
constexpr int GROUPS = 4;
constexpr int MAXK   = TQ + LOOKBACK - 1;  // 163
constexpr int NT     = L / TQ;             // 32

struct StageT {
    float xam[MAXK][49];   // x_amp rows, pad 49 (odd stride -> <=2-way banks)
    float xan[MAXK][33];   // x_ang rows (16 real + 16 imag), pad 33
};
struct TileT {
    float4 Ks[MAXK][8];    // swizzled: row r, slot s^(r&7)
    float4 Vs[MAXK][8];
    float4 Qs[TQ][6];
};
union SharedU { StageT stage; TileT t; };  // 53464 B

__global__ __launch_bounds__(256) void fused_qkv_attn_kernel(
    const float* __restrict__ x_ang, const float* __restrict__ x_amp,
    const float* __restrict__ Wq_amp, const float* __restrict__ Wk_amp,
    const float* __restrict__ Wv_amp,
    const float* __restrict__ Wq_ang_r, const float* __restrict__ Wq_ang_i,
    const float* __restrict__ Wk_ang_r, const float* __restrict__ Wk_ang_i,
    const float* __restrict__ Wv_ang_r, const float* __restrict__ Wv_ang_i,
    float* __restrict__ att)
{
    __shared__ SharedU u;
    __shared__ float  Pm[GROUPS][TQ];
    __shared__ float  Ps[GROUPS][TQ];
    __shared__ float4 Po[GROUPS][TQ][6];

    const int tid = threadIdx.x;
    const int bh  = blockIdx.x / NT;
    const int qt  = blockIdx.x % NT;
    const int b   = bh / H, h = bh % H;
    const int q0  = qt * TQ;
    int kmin = q0 - (LOOKBACK - 1); if (kmin < 0) kmin = 0;
    const int nrows = (q0 + TQ - 1) - kmin + 1;   // <= 163
    const int qoff  = q0 - kmin;                  // stage row of query 0

    // ---------------- Phase A: stage x ----------------
    {
        const float4* xm4 = (const float4*)(x_amp + ((size_t)b * L + kmin) * AMP);
        const float4* xg4 = (const float4*)(x_ang + ((size_t)b * L + kmin) * (2 * ANG));
        int namp = nrows * 12;
        int ntot = namp + nrows * 8;
        for (int c = tid; c < ntot; c += 256) {
            if (c < namp) {
                int r = c / 12, i = c % 12;
                float4 t = xm4[c];
                float* p = &u.stage.xam[r][4 * i];
                p[0] = t.x; p[1] = t.y; p[2] = t.z; p[3] = t.w;
            } else {
                int c2 = c - namp;
                int r = c2 / 8, i = c2 % 8;
                float4 t = xg4[c2];
                float* p = &u.stage.xan[r][4 * i];
                p[0] = t.x; p[1] = t.y; p[2] = t.z; p[3] = t.w;
            }
        }
    }
    __syncthreads();

    // ---------------- Phase B: projections into registers ----------------
    float4 kout[6], vout[6], qout[6];
    const bool kvact = (tid < nrows);
    const bool qact  = (tid >= 192);           // rows 192..255 -> q rows 0..63
    const int  qrow  = tid - 192;

    #pragma unroll
    for (int s = 0; s < 6; ++s) {
        if (kvact) {
            int r = tid;
            if (s >= 3) {
                int col4 = h * AQK + (s - 3) * 4;
                const float* Wk = Wk_amp + col4;
                const float* Wv = Wv_amp + col4;
                float4 ka = {0,0,0,0}, va = {0,0,0,0};
                #pragma unroll
                for (int i = 0; i < AMP; ++i) {
                    float x = u.stage.xam[r][i];
                    float4 wk = *(const float4*)(Wk + i * 48);
                    float4 wv = *(const float4*)(Wv + i * 48);
                    ka.x += x * wk.x; ka.y += x * wk.y; ka.z += x * wk.z; ka.w += x * wk.w;
                    va.x += x * wv.x; va.y += x * wv.y; va.z += x * wv.z; va.w += x * wv.w;
                }
                kout[s] = ka; vout[s] = va;
            } else {
                float kk[4], vv[4];
                #pragma unroll
                for (int c = 0; c < 4; ++c) {
                    int d = 4 * s + c;                 // 0..11
                    bool re = (d < GQK);
                    int dd = re ? d : d - GQK;
                    int col = h * GQK + dd;
                    const float* WkA = re ? Wk_ang_r : Wk_ang_i;
                    const float* WkB = re ? Wk_ang_i : Wk_ang_r;
                    const float* WvA = re ? Wv_ang_r : Wv_ang_i;
                    const float* WvB = re ? Wv_ang_i : Wv_ang_r;
                    float sgn = re ? -1.f : 1.f;
                    float ak = 0, bk = 0, aw = 0, bw = 0;
                    #pragma unroll
                    for (int i = 0; i < ANG; ++i) {
                        float xr = u.stage.xan[r][i];
                        float xi = u.stage.xan[r][16 + i];
                        ak += xr * WkA[i * 24 + col];  bk += xi * WkB[i * 24 + col];
                        aw += xr * WvA[i * 24 + col];  bw += xi * WvB[i * 24 + col];
                    }
                    kk[c] = ak + sgn * bk;  vv[c] = aw + sgn * bw;
                }
                kout[s] = make_float4(kk[0], kk[1], kk[2], kk[3]);
                vout[s] = make_float4(vv[0], vv[1], vv[2], vv[3]);
            }
        }
        if (qact) {
            int r = qoff + qrow;
            if (s >= 3) {
                int col4 = h * AQK + (s - 3) * 4;
                const float* Wq = Wq_amp + col4;
                float4 qa = {0,0,0,0};
                #pragma unroll
                for (int i = 0; i < AMP; ++i) {
                    float x = u.stage.xam[r][i];
                    float4 wq = *(const float4*)(Wq + i * 48);
                    qa.x += x * wq.x; qa.y += x * wq.y; qa.z += x * wq.z; qa.w += x * wq.w;
                }
                qout[s] = qa;
            } else {
                float qq[4];
                #pragma unroll
                for (int c = 0; c < 4; ++c) {
                    int d = 4 * s + c;
                    bool re = (d < GQK);
                    int dd = re ? d : d - GQK;
                    int col = h * GQK + dd;
                    const float* WA = re ? Wq_ang_r : Wq_ang_i;
                    const float* WB = re ? Wq_ang_i : Wq_ang_r;
                    float sgn = re ? -1.f : 1.f;
                    float aa = 0, bb = 0;
                    #pragma unroll
                    for (int i = 0; i < ANG; ++i) {
                        float xr = u.stage.xan[r][i];
                        float xi = u.stage.xan[r][16 + i];
                        aa += xr * WA[i * 24 + col];  bb += xi * WB[i * 24 + col];
                    }
                    qq[c] = aa + sgn * bb;
                }
                qout[s] = make_float4(qq[0], qq[1], qq[2], qq[3]);
            }
        }
    }
    __syncthreads();   // all stage reads complete

    // ---------------- Phase B2: write tiles (overwrites stage) ----------------
    if (kvact) {
        int r = tid, rx = r & 7;
        #pragma unroll
        for (int s = 0; s < 6; ++s) {
            u.t.Ks[r][s ^ rx] = kout[s];
            u.t.Vs[r][s ^ rx] = vout[s];
        }
    }
    if (qact) {
        #pragma unroll
        for (int s = 0; s < 6; ++s) u.t.Qs[qrow][s] = qout[s];
    }
    __syncthreads();

    // ---------------- Phase C: attention (attn3 core) ----------------
    const int qlocal = tid & (TQ - 1);
    const int group  = tid >> 6;          // 0..3
    const int qi = q0 + qlocal;

    float4 qr4[6];
    #pragma unroll
    for (int s = 0; s < 6; ++s) qr4[s] = u.t.Qs[qlocal][s];

    const float scale = 0.2041241452319315f; // 1/sqrt(24)
    float m = -3.0e38f, ss = 0.f;
    float4 o4[6];
    #pragma unroll
    for (int s = 0; s < 6; ++s) { o4[s].x = 0.f; o4[s].y = 0.f; o4[s].z = 0.f; o4[s].w = 0.f; }

    int j0 = qi - (LOOKBACK - 1); if (j0 < 0) j0 = 0;
    for (int j = j0 + group; j <= qi; j += GROUPS) {
        int r  = j - kmin;
        int rx = r & 7;
        float sc = 0.f;
        #pragma unroll
        for (int s = 0; s < 6; ++s) {
            float4 kk = u.t.Ks[r][s ^ rx];
            sc += qr4[s].x * kk.x + qr4[s].y * kk.y + qr4[s].z * kk.z + qr4[s].w * kk.w;
        }
        sc *= scale;
        float mn   = fmaxf(m, sc);
        float corr = __expf(m - mn);
        float p    = __expf(sc - mn);
        ss = ss * corr + p;
        #pragma unroll
        for (int s = 0; s < 6; ++s) {
            float4 vv = u.t.Vs[r][s ^ rx];
            o4[s].x = o4[s].x * corr + p * vv.x;
            o4[s].y = o4[s].y * corr + p * vv.y;
            o4[s].z = o4[s].z * corr + p * vv.z;
            o4[s].w = o4[s].w * corr + p * vv.w;
        }
        m = mn;
    }

    Pm[group][qlocal] = m;
    Ps[group][qlocal] = ss;
    #pragma unroll
    for (int s = 0; s < 6; ++s) Po[group][qlocal][s] = o4[s];
    __syncthreads();

    // parallel merge: 64 queries x 4 chunks; att token-major [tok][h][24]
    {
        int qq    = tid & 63;
        int chunk = tid >> 6;
        float m0 = Pm[0][qq], m1 = Pm[1][qq], m2 = Pm[2][qq], m3 = Pm[3][qq];
        float mm = fmaxf(fmaxf(m0, m1), fmaxf(m2, m3));
        float c0 = __expf(m0 - mm), c1 = __expf(m1 - mm);
        float c2 = __expf(m2 - mm), c3 = __expf(m3 - mm);
        float denom = Ps[0][qq] * c0 + Ps[1][qq] * c1 + Ps[2][qq] * c2 + Ps[3][qq] * c3;
        float inv = 1.f / denom;

        float4* op4 = (float4*)att + (size_t)(b * L + q0 + qq) * 6 * H / H * H; // placeholder avoided below
        op4 = (float4*)att + ((size_t)(b * L + q0 + qq) * H + h) * 0;           // (not used)
        // token-major: att[tok*96 + h*24 + d] -> float4 base tok*24 + h*6
        float4* dst = (float4*)att + (size_t)(b * L + q0 + qq) * 24 + h * 6;

        int s = chunk;
        {
            float4 a0 = Po[0][qq][s], a1 = Po[1][qq][s], a2 = Po[2][qq][s], a3 = Po[3][qq][s];
            float4 acc;
            acc.x = (a0.x * c0 + a1.x * c1 + a2.x * c2 + a3.x * c3) * inv;
            acc.y = (a0.y * c0 + a1.y * c1 + a2.y * c2 + a3.y * c3) * inv;
            acc.z = (a0.z * c0 + a1.z * c1 + a2.z * c2 + a3.z * c3) * inv;
            acc.w = (a0.w * c0 + a1.w * c1 + a2.w * c2 + a3.w * c3) * inv;
            dst[s] = acc;
        }
        if (chunk < 2) {
            s = chunk + 4;
            float4 a0 = Po[0][qq][s], a1 = Po[1][qq][s], a2 = Po[2][qq][s], a3 = Po[3][qq][s];
            float4 acc;
            acc.x = (a0.x * c0 + a1.x * c1 + a2.x * c2 + a3.x * c3) * inv;
            acc.y = (a0.y * c0 + a1.y * c1 + a2.y * c2 + a3.y * c3) * inv;
            acc.z = (a0.z * c0 + a1.z * c1 + a2.z * c2 + a3.z * c3) * inv;
            acc.w = (a0.w * c0 + a1.w * c1 + a2.w * c2 + a3.w * c3) * inv;
            dst[s] = acc;
        }
    }
}

// ---------------- Kernel 2: output projections (token-major att) ----------------
constexpr int PAMP_BLOCKS = (NTOK * 48) / 256;   // 3072
constexpr int PANG_BLOCKS = (NTOK * 16) / 256;   // 1024

__global__ __launch_bounds__(256) void proj3_kernel(
    const float* __restrict__ att,
    const float* __restrict__ Wout_amp, const float* __restrict__ bout_amp,
    const float* __restrict__ Wout_ang_r, const float* __restrict__ Wout_ang_i,
    float* __restrict__ out)
{
    constexpr size_t ANG_OUT = (size_t)NTOK * ANG; // 262144
    int bid = blockIdx.x;

    if (bid < PAMP_BLOCKS) {
        int g   = bid * 256 + threadIdx.x;
        int col = g % 48;
        int tok = g / 48;
        const float4* at4 = (const float4*)att + (size_t)tok * 24;

        float a[48];
        #pragma unroll
        for (int h = 0; h < H; h++) {
            #pragma unroll
            for (int i = 0; i < 3; i++) {
                float4 t = at4[h * 6 + 3 + i];
                a[h*12 + 4*i+0] = t.x; a[h*12 + 4*i+1] = t.y;
                a[h*12 + 4*i+2] = t.z; a[h*12 + 4*i+3] = t.w;
            }
        }
        float acc = bout_amp[col];
        #pragma unroll
        for (int i = 0; i < 48; i++)
            acc += a[i] * Wout_amp[i * AMP + col];
        out[2 * ANG_OUT + (size_t)tok * AMP + col] = acc;
    } else {
        int g   = (bid - PAMP_BLOCKS) * 256 + threadIdx.x;
        int col = g % 16;
        int tok = g / 16;
        const float4* at4 = (const float4*)att + (size_t)tok * 24;

        float ar[24], ai[24];
        #pragma unroll
        for (int h = 0; h < H; h++) {
            float4 t0 = at4[h*6+0], t1 = at4[h*6+1], t2 = at4[h*6+2];
            ar[h*6+0] = t0.x; ar[h*6+1] = t0.y; ar[h*6+2] = t0.z; ar[h*6+3] = t0.w;
            ar[h*6+4] = t1.x; ar[h*6+5] = t1.y;
            ai[h*6+0] = t1.z; ai[h*6+1] = t1.w;
            ai[h*6+2] = t2.x; ai[h*6+3] = t2.y; ai[h*6+4] = t2.z; ai[h*6+5] = t2.w;
        }
        float accr = 0.f, acci = 0.f;
        #pragma unroll
        for (int i = 0; i < 24; i++) {
            float wr = Wout_ang_r[i * ANG + col], wi = Wout_ang_i[i * ANG + col];
            accr += ar[i] * wr - ai[i] * wi;
            acci += ar[i] * wi + ai[i] * wr;
        }
        out[(size_t)tok * ANG + col]           = accr;
        out[ANG_OUT + (size_t)tok * ANG + col] = acci;
    }
}

// -------------------- Launch --------------------
extern "C" void kernel_launch(void* const* d_in, const int* in_sizes, int n_in,
                              void* d_out, int out_size, void* d_ws, size_t ws_size,
                              hipStream_t stream)
{
    const float* x_ang      = (const float*)d_in[0];
    const float* x_amp      = (const float*)d_in[1];
    const float* Wq_amp     = (const float*)d_in[2];
    const float* Wk_amp     = (const float*)d_in[3];
    const float* Wv_amp     = (const float*)d_in[4];
    const float* Wq_ang_r   = (const float*)d_in[5];
    const float* Wq_ang_i   = (const float*)d_in[6];
    const float* Wk_ang_r   = (const float*)d_in[7];
    const float* Wk_ang_i   = (const float*)d_in[8];
    const float* Wv_ang_r   = (const float*)d_in[9];
    const float* Wv_ang_i   = (const float*)d_in[10];
    const float* Wout_amp   = (const float*)d_in[11];
    const float* bout_amp   = (const float*)d_in[12];
    const float* Wout_ang_r = (const float*)d_in[13];
    const float* Wout_ang_i = (const float*)d_in[14];

    float* out = (float*)d_out;
    float* att = (float*)d_ws;   // NTOK * 96 floats = 6.29 MB, token-major

    fused_qkv_attn_kernel<<<B * H * NT, 256, 0, stream>>>(
        x_ang, x_amp, Wq_amp, Wk_amp, Wv_amp,
        Wq_ang_r, Wq_ang_i, Wk_ang_r, Wk_ang_i, Wv_ang_r, Wv_ang_i,
        att);

    proj3_kernel<<<PAMP_BLOCKS + PANG_BLOCKS, 256, 0, stream>>>(
        att, Wout_amp, bout_amp, Wout_ang_r, Wout_ang_i, out);
}